// Round 1
// baseline (2808.214 us; speedup 1.0000x reference)
//
#include <hip/hip_runtime.h>
#include <cmath>

#define NN 200000
#define NE 600000
#define FPD 128

// ---------------- ws layout (float offsets) ----------------
// x1   : [NN*128]            @ 0
// deg  : [NN] (int)          @ 25,600,000
// rwt0 : [128]               @ 25,800,000   rowsums of attend_w0
// rwh0 : [384]               @ 25,800,128   rowsums of whh0
// w0t  : [128*384]           @ 25,800,512   wih0^T (k-major)
// w1t  : [128*128]           @ 25,849,664   attend_w1^T (k-major)
// w2t  : [128*768]           @ 25,866,048   [wih1 | whh1]^T (k-major)
// total 25,964,352 floats = 103,857,408 bytes

__device__ __forceinline__ float sigm(float v) { return 1.0f / (1.0f + expf(-v)); }
__device__ __forceinline__ float eluf(float v) { return v > 0.0f ? v : expm1f(v); }

__global__ __launch_bounds__(256) void hist_kernel(const int* __restrict__ dst,
                                                   int* __restrict__ deg) {
  int e = blockIdx.x * 256 + threadIdx.x;
  if (e < NE) atomicAdd(&deg[dst[e]], 1);
}

// rowsums of attend_w0 (128 rows) and whh0 (384 rows); one block of 512
__global__ __launch_bounds__(512) void prep_kernel(const float* __restrict__ attw0,
                                                   const float* __restrict__ whh0,
                                                   float* __restrict__ rwt0,
                                                   float* __restrict__ rwh0) {
  int t = threadIdx.x;
  if (t < 128) {
    float s = 0.f;
    for (int k = 0; k < 128; k++) s += attw0[t * 128 + k];
    rwt0[t] = s;
  } else {
    int j = t - 128;  // 0..383
    float s = 0.f;
    for (int k = 0; k < 128; k++) s += whh0[j * 128 + k];
    rwh0[j] = s;
  }
}

// pre-transpose weights to k-major so LDS staging is coalesced + conflict-free
__global__ __launch_bounds__(256) void transpose_kernel(
    const float* __restrict__ wih0, const float* __restrict__ tw1,
    const float* __restrict__ wih1, const float* __restrict__ whh1,
    float* __restrict__ w0t, float* __restrict__ w1t, float* __restrict__ w2t) {
  int idx = blockIdx.x * 256 + threadIdx.x;
  if (idx < 49152) {                      // w0t: [128][384]
    int k = idx / 384, j = idx % 384;
    w0t[idx] = wih0[j * 128 + k];
  } else if (idx < 65536) {               // w1t: [128][128]
    int i2 = idx - 49152;
    int k = i2 / 128, j = i2 % 128;
    w1t[i2] = tw1[j * 128 + k];
  } else if (idx < 163840) {              // w2t: [128][768] = [wih1|whh1]^T
    int i2 = idx - 65536;
    int k = i2 / 768, j = i2 % 768;
    w2t[i2] = (j < 384) ? wih1[j * 128 + k] : whh1[(j - 384) * 128 + k];
  }
}

// ---------------- layer 0: per-node, BM=64 nodes/block, 512 threads ----------------
__global__ __launch_bounds__(512, 4) void layer0_kernel(
    const float* __restrict__ x, const float* __restrict__ tb0,
    const float* __restrict__ w0t, const float* __restrict__ bih0,
    const float* __restrict__ bhh0, const float* __restrict__ rwt0,
    const float* __restrict__ rwh0, const int* __restrict__ deg,
    float* __restrict__ x1) {
  __shared__ float s_lds[64];
  __shared__ float cs_lds[64][128];     // 32 KB
  __shared__ float w_lds[16 * 384];     // 24 KB, k-major chunk

  const int tid = threadIdx.x;
  const int n0 = blockIdx.x * 64;

  // 1) per-node feature sums: 8 threads/row, float4 loads, shfl-reduce groups of 8
  {
    int r = tid >> 3;
    int c = (tid & 7) << 4;
    const float4* xr = (const float4*)(x + (size_t)(n0 + r) * FPD + c);
    float a = 0.f;
#pragma unroll
    for (int q = 0; q < 4; q++) { float4 v = xr[q]; a += v.x + v.y + v.z + v.w; }
#pragma unroll
    for (int off = 1; off < 8; off <<= 1) a += __shfl_xor(a, off, 64);
    if ((tid & 7) == 0) s_lds[r] = a;
  }
  __syncthreads();

  // 2) cs0[n][k] = elu(s_n * rowsum(attend_w0)[k] + attend_b0[k])
  for (int idx = tid; idx < 64 * 128; idx += 512) {
    int n = idx >> 7, k = idx & 127;
    float v = fmaf(s_lds[n], rwt0[k], tb0[k]);
    cs_lds[n][k] = eluf(v);
  }
  __syncthreads();

  // 3) gi0 = cs0 @ wih0^T : per-thread tile 8 nodes x 2 cols x 3 gates
  const int tr = tid >> 6;   // wave id: nodes tr*8 .. tr*8+7 (wave-uniform => broadcast A reads)
  const int tc = tid & 63;   // cols j = tc*2, tc*2+1
  float acc[8][2][3] = {};

  for (int kc = 0; kc < 8; kc++) {
    for (int idx = tid; idx < 16 * 384; idx += 512)
      w_lds[idx] = w0t[kc * 6144 + idx];
    __syncthreads();
#pragma unroll
    for (int kk = 0; kk < 16; kk++) {
      float a[8];
#pragma unroll
      for (int i = 0; i < 8; i++) a[i] = cs_lds[tr * 8 + i][kc * 16 + kk];
      const float* wr0 = &w_lds[kk * 384];
      float2 wr = *(const float2*)&wr0[tc * 2];
      float2 wz = *(const float2*)&wr0[128 + tc * 2];
      float2 wn = *(const float2*)&wr0[256 + tc * 2];
#pragma unroll
      for (int i = 0; i < 8; i++) {
        acc[i][0][0] = fmaf(a[i], wr.x, acc[i][0][0]);
        acc[i][1][0] = fmaf(a[i], wr.y, acc[i][1][0]);
        acc[i][0][1] = fmaf(a[i], wz.x, acc[i][0][1]);
        acc[i][1][1] = fmaf(a[i], wz.y, acc[i][1][1]);
        acc[i][0][2] = fmaf(a[i], wn.x, acc[i][0][2]);
        acc[i][1][2] = fmaf(a[i], wn.y, acc[i][1][2]);
      }
    }
    __syncthreads();
  }

  // 4) GRU (h = s broadcast), scale by deg, write x1
#pragma unroll
  for (int i = 0; i < 8; i++) {
    int n = n0 + tr * 8 + i;
    float s = s_lds[tr * 8 + i];
    float dd = (float)deg[n];
    float om[2];
#pragma unroll
    for (int jj = 0; jj < 2; jj++) {
      int j = tc * 2 + jj;
      float gir = acc[i][jj][0] + bih0[j];
      float giz = acc[i][jj][1] + bih0[j + 128];
      float gin = acc[i][jj][2] + bih0[j + 256];
      float ghr = fmaf(s, rwh0[j], bhh0[j]);
      float ghz = fmaf(s, rwh0[j + 128], bhh0[j + 128]);
      float ghn = fmaf(s, rwh0[j + 256], bhh0[j + 256]);
      float r = sigm(gir + ghr);
      float z = sigm(giz + ghz);
      float nn = tanhf(fmaf(r, ghn, gin));
      om[jj] = dd * ((1.f - z) * nn + z * s);
    }
    float2 o = make_float2(om[0], om[1]);
    *(float2*)&x1[(size_t)n * FPD + tc * 2] = o;
  }
}

// ---------------- layer 1: per-node, BM=32 nodes/block, 512 threads ----------------
__global__ __launch_bounds__(512, 4) void layer1_kernel(
    const float* __restrict__ x1, const float* __restrict__ tb1,
    const float* __restrict__ w1t, const float* __restrict__ w2t,
    const float* __restrict__ bih1, const float* __restrict__ bhh1,
    const int* __restrict__ deg, float* __restrict__ out) {
  __shared__ float x_lds[32][128];    // 16 KB (h)
  __shared__ float cs_lds[32][128];   // 16 KB
  __shared__ float w_lds[8 * 768];    // 24 KB chunk (shared by both GEMMs)

  const int tid = threadIdx.x;
  const int n0 = blockIdx.x * 32;
  const int tr = tid >> 6;   // wave id: nodes tr*4 .. tr*4+3
  const int tc = tid & 63;   // cols j = tc*2, tc*2+1

  // stage x1 tile (coalesced float4)
  {
    const float4* src = (const float4*)(x1 + (size_t)n0 * FPD);
    float4* dst4 = (float4*)&x_lds[0][0];
    dst4[tid] = src[tid];
    dst4[tid + 512] = src[tid + 512];
  }
  __syncthreads();

  // GEMM1: t1 = X @ tw1^T ; cs = elu(t1 + tb1)
  float acc1[4][2] = {};
  for (int kc = 0; kc < 16; kc++) {
    for (int idx = tid; idx < 8 * 128; idx += 512)
      w_lds[idx] = w1t[kc * 1024 + idx];
    __syncthreads();
#pragma unroll
    for (int kk = 0; kk < 8; kk++) {
      float a[4];
#pragma unroll
      for (int i = 0; i < 4; i++) a[i] = x_lds[tr * 4 + i][kc * 8 + kk];
      float2 w = *(const float2*)&w_lds[kk * 128 + tc * 2];
#pragma unroll
      for (int i = 0; i < 4; i++) {
        acc1[i][0] = fmaf(a[i], w.x, acc1[i][0]);
        acc1[i][1] = fmaf(a[i], w.y, acc1[i][1]);
      }
    }
    __syncthreads();
  }
#pragma unroll
  for (int i = 0; i < 4; i++) {
#pragma unroll
    for (int jj = 0; jj < 2; jj++) {
      int j = tc * 2 + jj;
      cs_lds[tr * 4 + i][j] = eluf(acc1[i][jj] + tb1[j]);
    }
  }
  __syncthreads();

  // GEMM2: gi = cs @ wih1^T, gh = x @ whh1^T (6 gate rows per col)
  float acc2[4][2][6] = {};
  for (int kc = 0; kc < 16; kc++) {
    for (int idx = tid; idx < 8 * 768; idx += 512)
      w_lds[idx] = w2t[kc * 6144 + idx];
    __syncthreads();
#pragma unroll
    for (int kk = 0; kk < 8; kk++) {
      float ac[4], ah[4];
#pragma unroll
      for (int i = 0; i < 4; i++) {
        ac[i] = cs_lds[tr * 4 + i][kc * 8 + kk];
        ah[i] = x_lds[tr * 4 + i][kc * 8 + kk];
      }
      const float* wrow = &w_lds[kk * 768];
      float2 wir = *(const float2*)&wrow[tc * 2];
      float2 wiz = *(const float2*)&wrow[128 + tc * 2];
      float2 win = *(const float2*)&wrow[256 + tc * 2];
      float2 whr = *(const float2*)&wrow[384 + tc * 2];
      float2 whz = *(const float2*)&wrow[512 + tc * 2];
      float2 whn = *(const float2*)&wrow[640 + tc * 2];
#pragma unroll
      for (int i = 0; i < 4; i++) {
        acc2[i][0][0] = fmaf(ac[i], wir.x, acc2[i][0][0]);
        acc2[i][1][0] = fmaf(ac[i], wir.y, acc2[i][1][0]);
        acc2[i][0][1] = fmaf(ac[i], wiz.x, acc2[i][0][1]);
        acc2[i][1][1] = fmaf(ac[i], wiz.y, acc2[i][1][1]);
        acc2[i][0][2] = fmaf(ac[i], win.x, acc2[i][0][2]);
        acc2[i][1][2] = fmaf(ac[i], win.y, acc2[i][1][2]);
        acc2[i][0][3] = fmaf(ah[i], whr.x, acc2[i][0][3]);
        acc2[i][1][3] = fmaf(ah[i], whr.y, acc2[i][1][3]);
        acc2[i][0][4] = fmaf(ah[i], whz.x, acc2[i][0][4]);
        acc2[i][1][4] = fmaf(ah[i], whz.y, acc2[i][1][4]);
        acc2[i][0][5] = fmaf(ah[i], whn.x, acc2[i][0][5]);
        acc2[i][1][5] = fmaf(ah[i], whn.y, acc2[i][1][5]);
      }
    }
    __syncthreads();
  }

  // GRU finalize, scale by deg
#pragma unroll
  for (int i = 0; i < 4; i++) {
    int n = n0 + tr * 4 + i;
    float dd = (float)deg[n];
    float om[2];
#pragma unroll
    for (int jj = 0; jj < 2; jj++) {
      int j = tc * 2 + jj;
      float h = x_lds[tr * 4 + i][j];
      float gir = acc2[i][jj][0] + bih1[j];
      float giz = acc2[i][jj][1] + bih1[j + 128];
      float gin = acc2[i][jj][2] + bih1[j + 256];
      float ghr = acc2[i][jj][3] + bhh1[j];
      float ghz = acc2[i][jj][4] + bhh1[j + 128];
      float ghn = acc2[i][jj][5] + bhh1[j + 256];
      float r = sigm(gir + ghr);
      float z = sigm(giz + ghz);
      float nn = tanhf(fmaf(r, ghn, gin));
      om[jj] = dd * ((1.f - z) * nn + z * h);
    }
    float2 o = make_float2(om[0], om[1]);
    *(float2*)&out[(size_t)n * FPD + tc * 2] = o;
  }
}

extern "C" void kernel_launch(void* const* d_in, const int* in_sizes, int n_in,
                              void* d_out, int out_size, void* d_ws, size_t ws_size,
                              hipStream_t stream) {
  const float* x     = (const float*)d_in[0];
  const int*   edge  = (const int*)d_in[1];
  const float* attw0 = (const float*)d_in[4];
  const float* attb0 = (const float*)d_in[5];
  const float* wih0  = (const float*)d_in[6];
  const float* whh0  = (const float*)d_in[7];
  const float* bih0  = (const float*)d_in[8];
  const float* bhh0  = (const float*)d_in[9];
  const float* attw1 = (const float*)d_in[12];
  const float* attb1 = (const float*)d_in[13];
  const float* wih1  = (const float*)d_in[14];
  const float* whh1  = (const float*)d_in[15];
  const float* bih1  = (const float*)d_in[16];
  const float* bhh1  = (const float*)d_in[17];

  float* ws   = (float*)d_ws;
  float* x1   = ws;
  int*   deg  = (int*)(ws + 25600000);
  float* rwt0 = ws + 25800000;
  float* rwh0 = ws + 25800128;
  float* w0t  = ws + 25800512;
  float* w1t  = ws + 25849664;
  float* w2t  = ws + 25866048;

  const int* dst = edge + NE;  // edge_index[1]

  hipMemsetAsync(deg, 0, NN * sizeof(int), stream);
  hist_kernel<<<(NE + 255) / 256, 256, 0, stream>>>(dst, deg);
  prep_kernel<<<1, 512, 0, stream>>>(attw0, whh0, rwt0, rwh0);
  transpose_kernel<<<640, 256, 0, stream>>>(wih0, attw1, wih1, whh1, w0t, w1t, w2t);
  layer0_kernel<<<NN / 64, 512, 0, stream>>>(x, attb0, w0t, bih0, bhh0, rwt0, rwh0, deg, x1);
  layer1_kernel<<<NN / 32, 512, 0, stream>>>(x1, attb1, w1t, w2t, bih1, bhh1, deg, (float*)d_out);
}

// Round 2
// 2249.101 us; speedup vs baseline: 1.2486x; 1.2486x over previous
//
#include <hip/hip_runtime.h>
#include <cmath>

#define NN 200000
#define NE 600000
#define FPD 128

// ---------------- ws layout (float offsets) ----------------
// x1   : [NN*128]            @ 0
// deg  : [NN] (int)          @ 25,600,000
// rwt0 : [128]               @ 25,800,000   rowsums of attend_w0
// rwh0 : [384]               @ 25,800,128   rowsums of whh0
// w0t  : [128*384]           @ 25,800,512   wih0^T (k-major)
// w1t  : [128*128]           @ 25,849,664   attend_w1^T (k-major)
// w2t  : [128*768]           @ 25,866,048   [wih1 | whh1]^T (k-major)

__device__ __forceinline__ float sigm(float v) { return 1.0f / (1.0f + expf(-v)); }
__device__ __forceinline__ float eluf(float v) { return v > 0.0f ? v : expm1f(v); }

__global__ __launch_bounds__(256) void hist_kernel(const int* __restrict__ dst,
                                                   int* __restrict__ deg) {
  int e = blockIdx.x * 256 + threadIdx.x;
  if (e < NE) atomicAdd(&deg[dst[e]], 1);
}

// rowsums of attend_w0 (128 rows) and whh0 (384 rows); one block of 512
__global__ __launch_bounds__(512) void prep_kernel(const float* __restrict__ attw0,
                                                   const float* __restrict__ whh0,
                                                   float* __restrict__ rwt0,
                                                   float* __restrict__ rwh0) {
  int t = threadIdx.x;
  if (t < 128) {
    float s = 0.f;
    for (int k = 0; k < 128; k++) s += attw0[t * 128 + k];
    rwt0[t] = s;
  } else {
    int j = t - 128;  // 0..383
    float s = 0.f;
    for (int k = 0; k < 128; k++) s += whh0[j * 128 + k];
    rwh0[j] = s;
  }
}

// pre-transpose weights to k-major so LDS staging is coalesced + conflict-free
__global__ __launch_bounds__(256) void transpose_kernel(
    const float* __restrict__ wih0, const float* __restrict__ tw1,
    const float* __restrict__ wih1, const float* __restrict__ whh1,
    float* __restrict__ w0t, float* __restrict__ w1t, float* __restrict__ w2t) {
  int idx = blockIdx.x * 256 + threadIdx.x;
  if (idx < 49152) {                      // w0t: [128][384]
    int k = idx / 384, j = idx % 384;
    w0t[idx] = wih0[j * 128 + k];
  } else if (idx < 65536) {               // w1t: [128][128]
    int i2 = idx - 49152;
    int k = i2 / 128, j = i2 % 128;
    w1t[i2] = tw1[j * 128 + k];
  } else if (idx < 163840) {              // w2t: [128][768] = [wih1|whh1]^T
    int i2 = idx - 65536;
    int k = i2 / 768, j = i2 % 768;
    w2t[i2] = (j < 384) ? wih1[j * 128 + k] : whh1[(j - 384) * 128 + k];
  }
}

// ---------------- layer 0: per-node, BM=64 nodes/block, 512 threads ----------------
// launch_bounds (512, 2): VGPR cap 256/wave. (512,4) capped at 64 VGPRs and
// spilled the 48-float accumulator tile to scratch -> 5.3 GB of HBM writes.
__global__ __launch_bounds__(512, 2) void layer0_kernel(
    const float* __restrict__ x, const float* __restrict__ tb0,
    const float* __restrict__ w0t, const float* __restrict__ bih0,
    const float* __restrict__ bhh0, const float* __restrict__ rwt0,
    const float* __restrict__ rwh0, const int* __restrict__ deg,
    float* __restrict__ x1) {
  __shared__ float s_lds[64];
  __shared__ float cs_lds[64][128];     // 32 KB
  __shared__ float w_lds[16 * 384];     // 24 KB, k-major chunk

  const int tid = threadIdx.x;
  const int n0 = blockIdx.x * 64;

  // 1) per-node feature sums: 8 threads/row, float4 loads, shfl-reduce groups of 8
  {
    int r = tid >> 3;
    int c = (tid & 7) << 4;
    const float4* xr = (const float4*)(x + (size_t)(n0 + r) * FPD + c);
    float a = 0.f;
#pragma unroll
    for (int q = 0; q < 4; q++) { float4 v = xr[q]; a += v.x + v.y + v.z + v.w; }
#pragma unroll
    for (int off = 1; off < 8; off <<= 1) a += __shfl_xor(a, off, 64);
    if ((tid & 7) == 0) s_lds[r] = a;
  }
  __syncthreads();

  // 2) cs0[n][k] = elu(s_n * rowsum(attend_w0)[k] + attend_b0[k])
  for (int idx = tid; idx < 64 * 128; idx += 512) {
    int n = idx >> 7, k = idx & 127;
    float v = fmaf(s_lds[n], rwt0[k], tb0[k]);
    cs_lds[n][k] = eluf(v);
  }
  __syncthreads();

  // 3) gi0 = cs0 @ wih0^T : per-thread tile 8 nodes x 2 cols x 3 gates
  const int tr = tid >> 6;   // wave id: nodes tr*8 .. tr*8+7 (wave-uniform => broadcast A reads)
  const int tc = tid & 63;   // cols j = tc*2, tc*2+1
  float acc[8][2][3] = {};

  for (int kc = 0; kc < 8; kc++) {
    for (int idx = tid; idx < 16 * 384; idx += 512)
      w_lds[idx] = w0t[kc * 6144 + idx];
    __syncthreads();
#pragma unroll
    for (int kk = 0; kk < 16; kk++) {
      float a[8];
#pragma unroll
      for (int i = 0; i < 8; i++) a[i] = cs_lds[tr * 8 + i][kc * 16 + kk];
      const float* wr0 = &w_lds[kk * 384];
      float2 wr = *(const float2*)&wr0[tc * 2];
      float2 wz = *(const float2*)&wr0[128 + tc * 2];
      float2 wn = *(const float2*)&wr0[256 + tc * 2];
#pragma unroll
      for (int i = 0; i < 8; i++) {
        acc[i][0][0] = fmaf(a[i], wr.x, acc[i][0][0]);
        acc[i][1][0] = fmaf(a[i], wr.y, acc[i][1][0]);
        acc[i][0][1] = fmaf(a[i], wz.x, acc[i][0][1]);
        acc[i][1][1] = fmaf(a[i], wz.y, acc[i][1][1]);
        acc[i][0][2] = fmaf(a[i], wn.x, acc[i][0][2]);
        acc[i][1][2] = fmaf(a[i], wn.y, acc[i][1][2]);
      }
    }
    __syncthreads();
  }

  // 4) GRU (h = s broadcast), scale by deg, write x1
#pragma unroll
  for (int i = 0; i < 8; i++) {
    int n = n0 + tr * 8 + i;
    float s = s_lds[tr * 8 + i];
    float dd = (float)deg[n];
    float om[2];
#pragma unroll
    for (int jj = 0; jj < 2; jj++) {
      int j = tc * 2 + jj;
      float gir = acc[i][jj][0] + bih0[j];
      float giz = acc[i][jj][1] + bih0[j + 128];
      float gin = acc[i][jj][2] + bih0[j + 256];
      float ghr = fmaf(s, rwh0[j], bhh0[j]);
      float ghz = fmaf(s, rwh0[j + 128], bhh0[j + 128]);
      float ghn = fmaf(s, rwh0[j + 256], bhh0[j + 256]);
      float r = sigm(gir + ghr);
      float z = sigm(giz + ghz);
      float nn = tanhf(fmaf(r, ghn, gin));
      om[jj] = dd * ((1.f - z) * nn + z * s);
    }
    float2 o = make_float2(om[0], om[1]);
    *(float2*)&x1[(size_t)n * FPD + tc * 2] = o;
  }
}

// ---------------- layer 1: per-node, BM=32 nodes/block, 512 threads ----------------
__global__ __launch_bounds__(512, 2) void layer1_kernel(
    const float* __restrict__ x1, const float* __restrict__ tb1,
    const float* __restrict__ w1t, const float* __restrict__ w2t,
    const float* __restrict__ bih1, const float* __restrict__ bhh1,
    const int* __restrict__ deg, float* __restrict__ out) {
  __shared__ float x_lds[32][128];    // 16 KB (h)
  __shared__ float cs_lds[32][128];   // 16 KB
  __shared__ float w_lds[8 * 768];    // 24 KB chunk (shared by both GEMMs)

  const int tid = threadIdx.x;
  const int n0 = blockIdx.x * 32;
  const int tr = tid >> 6;   // wave id: nodes tr*4 .. tr*4+3
  const int tc = tid & 63;   // cols j = tc*2, tc*2+1

  // stage x1 tile (coalesced float4)
  {
    const float4* src = (const float4*)(x1 + (size_t)n0 * FPD);
    float4* dst4 = (float4*)&x_lds[0][0];
    dst4[tid] = src[tid];
    dst4[tid + 512] = src[tid + 512];
  }
  __syncthreads();

  // GEMM1: t1 = X @ tw1^T ; cs = elu(t1 + tb1)
  float acc1[4][2] = {};
  for (int kc = 0; kc < 16; kc++) {
    for (int idx = tid; idx < 8 * 128; idx += 512)
      w_lds[idx] = w1t[kc * 1024 + idx];
    __syncthreads();
#pragma unroll
    for (int kk = 0; kk < 8; kk++) {
      float a[4];
#pragma unroll
      for (int i = 0; i < 4; i++) a[i] = x_lds[tr * 4 + i][kc * 8 + kk];
      float2 w = *(const float2*)&w_lds[kk * 128 + tc * 2];
#pragma unroll
      for (int i = 0; i < 4; i++) {
        acc1[i][0] = fmaf(a[i], w.x, acc1[i][0]);
        acc1[i][1] = fmaf(a[i], w.y, acc1[i][1]);
      }
    }
    __syncthreads();
  }
#pragma unroll
  for (int i = 0; i < 4; i++) {
#pragma unroll
    for (int jj = 0; jj < 2; jj++) {
      int j = tc * 2 + jj;
      cs_lds[tr * 4 + i][j] = eluf(acc1[i][jj] + tb1[j]);
    }
  }
  __syncthreads();

  // GEMM2: gi = cs @ wih1^T, gh = x @ whh1^T (6 gate rows per col)
  float acc2[4][2][6] = {};
  for (int kc = 0; kc < 16; kc++) {
    for (int idx = tid; idx < 8 * 768; idx += 512)
      w_lds[idx] = w2t[kc * 6144 + idx];
    __syncthreads();
#pragma unroll
    for (int kk = 0; kk < 8; kk++) {
      float ac[4], ah[4];
#pragma unroll
      for (int i = 0; i < 4; i++) {
        ac[i] = cs_lds[tr * 4 + i][kc * 8 + kk];
        ah[i] = x_lds[tr * 4 + i][kc * 8 + kk];
      }
      const float* wrow = &w_lds[kk * 768];
      float2 wir = *(const float2*)&wrow[tc * 2];
      float2 wiz = *(const float2*)&wrow[128 + tc * 2];
      float2 win = *(const float2*)&wrow[256 + tc * 2];
      float2 whr = *(const float2*)&wrow[384 + tc * 2];
      float2 whz = *(const float2*)&wrow[512 + tc * 2];
      float2 whn = *(const float2*)&wrow[640 + tc * 2];
#pragma unroll
      for (int i = 0; i < 4; i++) {
        acc2[i][0][0] = fmaf(ac[i], wir.x, acc2[i][0][0]);
        acc2[i][1][0] = fmaf(ac[i], wir.y, acc2[i][1][0]);
        acc2[i][0][1] = fmaf(ac[i], wiz.x, acc2[i][0][1]);
        acc2[i][1][1] = fmaf(ac[i], wiz.y, acc2[i][1][1]);
        acc2[i][0][2] = fmaf(ac[i], win.x, acc2[i][0][2]);
        acc2[i][1][2] = fmaf(ac[i], win.y, acc2[i][1][2]);
        acc2[i][0][3] = fmaf(ah[i], whr.x, acc2[i][0][3]);
        acc2[i][1][3] = fmaf(ah[i], whr.y, acc2[i][1][3]);
        acc2[i][0][4] = fmaf(ah[i], whz.x, acc2[i][0][4]);
        acc2[i][1][4] = fmaf(ah[i], whz.y, acc2[i][1][4]);
        acc2[i][0][5] = fmaf(ah[i], whn.x, acc2[i][0][5]);
        acc2[i][1][5] = fmaf(ah[i], whn.y, acc2[i][1][5]);
      }
    }
    __syncthreads();
  }

  // GRU finalize, scale by deg
#pragma unroll
  for (int i = 0; i < 4; i++) {
    int n = n0 + tr * 4 + i;
    float dd = (float)deg[n];
    float om[2];
#pragma unroll
    for (int jj = 0; jj < 2; jj++) {
      int j = tc * 2 + jj;
      float h = x_lds[tr * 4 + i][j];
      float gir = acc2[i][jj][0] + bih1[j];
      float giz = acc2[i][jj][1] + bih1[j + 128];
      float gin = acc2[i][jj][2] + bih1[j + 256];
      float ghr = acc2[i][jj][3] + bhh1[j];
      float ghz = acc2[i][jj][4] + bhh1[j + 128];
      float ghn = acc2[i][jj][5] + bhh1[j + 256];
      float r = sigm(gir + ghr);
      float z = sigm(giz + ghz);
      float nn = tanhf(fmaf(r, ghn, gin));
      om[jj] = dd * ((1.f - z) * nn + z * h);
    }
    float2 o = make_float2(om[0], om[1]);
    *(float2*)&out[(size_t)n * FPD + tc * 2] = o;
  }
}

extern "C" void kernel_launch(void* const* d_in, const int* in_sizes, int n_in,
                              void* d_out, int out_size, void* d_ws, size_t ws_size,
                              hipStream_t stream) {
  const float* x     = (const float*)d_in[0];
  const int*   edge  = (const int*)d_in[1];
  const float* attw0 = (const float*)d_in[4];
  const float* attb0 = (const float*)d_in[5];
  const float* wih0  = (const float*)d_in[6];
  const float* whh0  = (const float*)d_in[7];
  const float* bih0  = (const float*)d_in[8];
  const float* bhh0  = (const float*)d_in[9];
  const float* attw1 = (const float*)d_in[12];
  const float* attb1 = (const float*)d_in[13];
  const float* wih1  = (const float*)d_in[14];
  const float* whh1  = (const float*)d_in[15];
  const float* bih1  = (const float*)d_in[16];
  const float* bhh1  = (const float*)d_in[17];

  float* ws   = (float*)d_ws;
  float* x1   = ws;
  int*   deg  = (int*)(ws + 25600000);
  float* rwt0 = ws + 25800000;
  float* rwh0 = ws + 25800128;
  float* w0t  = ws + 25800512;
  float* w1t  = ws + 25849664;
  float* w2t  = ws + 25866048;

  const int* dst = edge + NE;  // edge_index[1]

  hipMemsetAsync(deg, 0, NN * sizeof(int), stream);
  hist_kernel<<<(NE + 255) / 256, 256, 0, stream>>>(dst, deg);
  prep_kernel<<<1, 512, 0, stream>>>(attw0, whh0, rwt0, rwh0);
  transpose_kernel<<<640, 256, 0, stream>>>(wih0, attw1, wih1, whh1, w0t, w1t, w2t);
  layer0_kernel<<<NN / 64, 512, 0, stream>>>(x, attb0, w0t, bih0, bhh0, rwt0, rwh0, deg, x1);
  layer1_kernel<<<NN / 32, 512, 0, stream>>>(x1, attb1, w1t, w2t, bih1, bhh1, deg, (float*)d_out);
}

// Round 4
// 577.274 us; speedup vs baseline: 4.8646x; 3.8961x over previous
//
#include <hip/hip_runtime.h>
#include <cmath>

#define NN 200000
#define NE 600000

typedef __bf16 bf16x8 __attribute__((ext_vector_type(8)));
typedef float f32x4 __attribute__((ext_vector_type(4)));

__device__ __forceinline__ float sigm(float v) { return 1.0f / (1.0f + expf(-v)); }
__device__ __forceinline__ float eluf(float v) { return v > 0.0f ? v : expm1f(v); }
__device__ __forceinline__ unsigned short bfr(float f) {  // f32 -> bf16 RNE
  unsigned u = __float_as_uint(f);
  u += 0x7FFFu + ((u >> 16) & 1u);
  return (unsigned short)(u >> 16);
}
// split fp32 into hi+lo bf16 (exact to ~2^-18 relative)
__device__ __forceinline__ void bsplit(float v, unsigned short& hi, unsigned short& lo) {
  unsigned short h = bfr(v);
  float hf = __uint_as_float(((unsigned)h) << 16);
  hi = h;
  lo = bfr(v - hf);
}

// ---------------- ws layout (float offsets) ----------------
// x1 [25,600,000] @0 ; deg(int)[200,000] @25,600,000 ; rwt0[128] @25,800,000 ;
// rwh0[384] @25,800,128 ; packed bf16 weight frags (shorts) @float 25,800,512:
//   w0ph 49152 | w0pl 49152 | w1ph 16384 | w1pl 16384 | w2ph 98304 | w2pl 98304
// total = 25,964,352 floats (same footprint as R1/R2)

__global__ __launch_bounds__(256) void hist_kernel(const int* __restrict__ dst,
                                                   int* __restrict__ deg) {
  int e = blockIdx.x * 256 + threadIdx.x;
  if (e < NE) atomicAdd(&deg[dst[e]], 1);
}

__global__ __launch_bounds__(512) void prep_kernel(const float* __restrict__ attw0,
                                                   const float* __restrict__ whh0,
                                                   float* __restrict__ rwt0,
                                                   float* __restrict__ rwh0) {
  int t = threadIdx.x;
  if (t < 128) {
    float s = 0.f;
    for (int k = 0; k < 128; k++) s += attw0[t * 128 + k];
    rwt0[t] = s;
  } else {
    int j = t - 128;
    float s = 0.f;
    for (int k = 0; k < 128; k++) s += whh0[j * 128 + k];
    rwh0[j] = s;
  }
}

// Pack weights into MFMA B-fragment order, split hi/lo bf16:
// frag[((nt*4+ks)*64+lane)*8 + j] = W[nt*16+(lane&15)][ks*32+(lane>>4)*8+j]
__global__ __launch_bounds__(256) void pack_kernel(
    const float* __restrict__ wih0, const float* __restrict__ tw1,
    const float* __restrict__ wih1, const float* __restrict__ whh1,
    unsigned short* __restrict__ w0ph, unsigned short* __restrict__ w0pl,
    unsigned short* __restrict__ w1ph, unsigned short* __restrict__ w1pl,
    unsigned short* __restrict__ w2ph, unsigned short* __restrict__ w2pl) {
  int g = blockIdx.x * 256 + threadIdx.x;  // one 8-element lane-frag
  unsigned short *PH, *PL;
  const float* row;
  int l;
  if (g < 6144) { l = g; PH = w0ph; PL = w0pl; }
  else if (g < 8192) { l = g - 6144; PH = w1ph; PL = w1pl; }
  else if (g < 20480) { l = g - 8192; PH = w2ph; PL = w2pl; }
  else return;
  int lane = l & 63, ks = (l >> 6) & 3, nt = l >> 8;
  int n = nt * 16 + (lane & 15);
  int k0 = ks * 32 + (lane >> 4) * 8;
  if (g < 6144) row = wih0 + n * 128;
  else if (g < 8192) row = tw1 + n * 128;
  else row = (n < 384) ? wih1 + n * 128 : whh1 + (n - 384) * 128;
  unsigned uh[4], ul[4];
  for (int p = 0; p < 4; p++) {
    unsigned short ah, al, bh, bl;
    bsplit(row[k0 + 2 * p], ah, al);
    bsplit(row[k0 + 2 * p + 1], bh, bl);
    uh[p] = (unsigned)ah | ((unsigned)bh << 16);
    ul[p] = (unsigned)al | ((unsigned)bl << 16);
  }
  *(uint4*)&PH[l * 8] = make_uint4(uh[0], uh[1], uh[2], uh[3]);
  *(uint4*)&PL[l * 8] = make_uint4(ul[0], ul[1], ul[2], ul[3]);
}

#define MFMA3(accv, ah, al, bh, bl)                                          \
  accv = __builtin_amdgcn_mfma_f32_16x16x32_bf16(ah, bh, accv, 0, 0, 0);     \
  accv = __builtin_amdgcn_mfma_f32_16x16x32_bf16(ah, bl, accv, 0, 0, 0);     \
  accv = __builtin_amdgcn_mfma_f32_16x16x32_bf16(al, bh, accv, 0, 0, 0);

// ---------------- layer 0: M=32 nodes/block, 256 threads (4 waves) ----------------
__global__ __launch_bounds__(256, 2) void layer0_kernel(
    const float* __restrict__ x, const float* __restrict__ tb0,
    const unsigned short* __restrict__ w0ph, const unsigned short* __restrict__ w0pl,
    const float* __restrict__ bih0, const float* __restrict__ bhh0,
    const float* __restrict__ rwt0, const float* __restrict__ rwh0,
    const int* __restrict__ deg, float* __restrict__ x1) {
  __shared__ float s_lds[32];
  __shared__ float deg_lds[32];
  __shared__ unsigned short csh[32 * 136];  // stride 272 B = 16B-aligned rows
  __shared__ unsigned short csl[32 * 136];

  const int tid = threadIdx.x;
  const int lane = tid & 63;
  const int wv = tid >> 6;
  const int n0 = blockIdx.x * 32;

  if (tid < 32) deg_lds[tid] = (float)deg[n0 + tid];

  // s_m = rowsum(x[m])
  {
    int m = tid >> 3, c = (tid & 7) * 16;
    const float4* xr = (const float4*)(x + (size_t)(n0 + m) * 128 + c);
    float a = 0.f;
#pragma unroll
    for (int q = 0; q < 4; q++) { float4 v = xr[q]; a += v.x + v.y + v.z + v.w; }
#pragma unroll
    for (int o = 1; o < 8; o <<= 1) a += __shfl_xor(a, o, 64);
    if ((tid & 7) == 0) s_lds[m] = a;
  }
  __syncthreads();

  // cs0[m][k] = elu(s_m * rwt0[k] + tb0[k]) -> split bf16 LDS
  {
    int m = tid >> 3, c0 = (tid & 7) * 16;
    float s = s_lds[m];
#pragma unroll
    for (int q = 0; q < 4; q++) {
      int k = c0 + q * 4;
      unsigned short h0, l0, h1, l1, h2, l2, h3, l3;
      bsplit(eluf(fmaf(s, rwt0[k], tb0[k])), h0, l0);
      bsplit(eluf(fmaf(s, rwt0[k + 1], tb0[k + 1])), h1, l1);
      bsplit(eluf(fmaf(s, rwt0[k + 2], tb0[k + 2])), h2, l2);
      bsplit(eluf(fmaf(s, rwt0[k + 3], tb0[k + 3])), h3, l3);
      *(uint2*)&csh[m * 136 + k] =
          make_uint2((unsigned)h0 | ((unsigned)h1 << 16), (unsigned)h2 | ((unsigned)h3 << 16));
      *(uint2*)&csl[m * 136 + k] =
          make_uint2((unsigned)l0 | ((unsigned)l1 << 16), (unsigned)l2 | ((unsigned)l3 << 16));
    }
  }
  __syncthreads();

  // gi = cs0 @ wih0^T via split-bf16 MFMA
  const int mrow = lane & 15;
  const int kq = (lane >> 4) * 8;
  const int quad = lane >> 4;
  f32x4 acc[2][2][3] = {};
#pragma unroll
  for (int ks = 0; ks < 4; ks++) {
    bf16x8 a0h = *(const bf16x8*)&csh[mrow * 136 + ks * 32 + kq];
    bf16x8 a0l = *(const bf16x8*)&csl[mrow * 136 + ks * 32 + kq];
    bf16x8 a1h = *(const bf16x8*)&csh[(16 + mrow) * 136 + ks * 32 + kq];
    bf16x8 a1l = *(const bf16x8*)&csl[(16 + mrow) * 136 + ks * 32 + kq];
#pragma unroll
    for (int jj = 0; jj < 2; jj++) {
      int jt = wv + jj * 4;
#pragma unroll
      for (int g = 0; g < 3; g++) {
        int nt = g * 8 + jt;
        size_t base = (size_t)((nt * 4 + ks) * 64 + lane) * 8;
        bf16x8 bh = *(const bf16x8*)&w0ph[base];
        bf16x8 bl = *(const bf16x8*)&w0pl[base];
        MFMA3(acc[0][jj][g], a0h, a0l, bh, bl);
        MFMA3(acc[1][jj][g], a1h, a1l, bh, bl);
      }
    }
  }

  // GRU epilogue (h = s broadcast, gh = s*rwh0 + bhh0), scale by deg
  float bir[2], biz[2], bin_[2], bhr[2], bhz[2], bhn[2], rwr[2], rwz[2], rwn[2];
#pragma unroll
  for (int jj = 0; jj < 2; jj++) {
    int j = (wv + jj * 4) * 16 + mrow;
    bir[jj] = bih0[j]; biz[jj] = bih0[j + 128]; bin_[jj] = bih0[j + 256];
    bhr[jj] = bhh0[j]; bhz[jj] = bhh0[j + 128]; bhn[jj] = bhh0[j + 256];
    rwr[jj] = rwh0[j]; rwz[jj] = rwh0[j + 128]; rwn[jj] = rwh0[j + 256];
  }
#pragma unroll
  for (int mt = 0; mt < 2; mt++) {
#pragma unroll
    for (int reg = 0; reg < 4; reg++) {
      int m = mt * 16 + quad * 4 + reg;
      float s = s_lds[m];
      float dd = deg_lds[m];
#pragma unroll
      for (int jj = 0; jj < 2; jj++) {
        float gir = acc[mt][jj][0][reg] + bir[jj];
        float giz = acc[mt][jj][1][reg] + biz[jj];
        float gin = acc[mt][jj][2][reg] + bin_[jj];
        float ghr = fmaf(s, rwr[jj], bhr[jj]);
        float ghz = fmaf(s, rwz[jj], bhz[jj]);
        float ghn = fmaf(s, rwn[jj], bhn[jj]);
        float r = sigm(gir + ghr);
        float z = sigm(giz + ghz);
        float nn = tanhf(fmaf(r, ghn, gin));
        int j = (wv + jj * 4) * 16 + mrow;
        x1[(size_t)(n0 + m) * 128 + j] = dd * ((1.f - z) * nn + z * s);
      }
    }
  }
}

// ---------------- layer 1: M=32 nodes/block, 256 threads (4 waves) ----------------
__global__ __launch_bounds__(256, 2) void layer1_kernel(
    const float* __restrict__ x1, const float* __restrict__ tb1,
    const unsigned short* __restrict__ w1ph, const unsigned short* __restrict__ w1pl,
    const unsigned short* __restrict__ w2ph, const unsigned short* __restrict__ w2pl,
    const float* __restrict__ bih1, const float* __restrict__ bhh1,
    const int* __restrict__ deg, float* __restrict__ out) {
  __shared__ unsigned short hh[32 * 136];
  __shared__ unsigned short hl[32 * 136];
  __shared__ unsigned short ch[32 * 136];
  __shared__ unsigned short cl[32 * 136];
  __shared__ float deg_lds[32];

  const int tid = threadIdx.x;
  const int lane = tid & 63;
  const int wv = tid >> 6;
  const int n0 = blockIdx.x * 32;
  const int mrow = lane & 15;
  const int kq = (lane >> 4) * 8;
  const int quad = lane >> 4;

  if (tid < 32) deg_lds[tid] = (float)deg[n0 + tid];

  // stage h = x1 tile, split bf16
  {
    int m = tid >> 3, c0 = (tid & 7) * 16;
    const float4* xr = (const float4*)(x1 + (size_t)(n0 + m) * 128 + c0);
#pragma unroll
    for (int q = 0; q < 4; q++) {
      float4 v = xr[q];
      unsigned short h0, l0, h1, l1, h2, l2, h3, l3;
      bsplit(v.x, h0, l0); bsplit(v.y, h1, l1);
      bsplit(v.z, h2, l2); bsplit(v.w, h3, l3);
      *(uint2*)&hh[m * 136 + c0 + q * 4] =
          make_uint2((unsigned)h0 | ((unsigned)h1 << 16), (unsigned)h2 | ((unsigned)h3 << 16));
      *(uint2*)&hl[m * 136 + c0 + q * 4] =
          make_uint2((unsigned)l0 | ((unsigned)l1 << 16), (unsigned)l2 | ((unsigned)l3 << 16));
    }
  }
  __syncthreads();

  // GEMM1: t1 = h @ tw1^T ; cs = elu(t1 + tb1) -> split bf16 LDS
  f32x4 acc1[2][2] = {};
#pragma unroll
  for (int ks = 0; ks < 4; ks++) {
    bf16x8 a0h = *(const bf16x8*)&hh[mrow * 136 + ks * 32 + kq];
    bf16x8 a0l = *(const bf16x8*)&hl[mrow * 136 + ks * 32 + kq];
    bf16x8 a1h = *(const bf16x8*)&hh[(16 + mrow) * 136 + ks * 32 + kq];
    bf16x8 a1l = *(const bf16x8*)&hl[(16 + mrow) * 136 + ks * 32 + kq];
#pragma unroll
    for (int jj = 0; jj < 2; jj++) {
      int nt = wv + jj * 4;
      size_t base = (size_t)((nt * 4 + ks) * 64 + lane) * 8;
      bf16x8 bh = *(const bf16x8*)&w1ph[base];
      bf16x8 bl = *(const bf16x8*)&w1pl[base];
      MFMA3(acc1[0][jj], a0h, a0l, bh, bl);
      MFMA3(acc1[1][jj], a1h, a1l, bh, bl);
    }
  }
  {
    float tbj[2];
#pragma unroll
    for (int jj = 0; jj < 2; jj++) tbj[jj] = tb1[(wv + jj * 4) * 16 + mrow];
#pragma unroll
    for (int mt = 0; mt < 2; mt++)
#pragma unroll
      for (int jj = 0; jj < 2; jj++)
#pragma unroll
        for (int reg = 0; reg < 4; reg++) {
          int m = mt * 16 + quad * 4 + reg;
          int j = (wv + jj * 4) * 16 + mrow;
          unsigned short vh, vl;
          bsplit(eluf(acc1[mt][jj][reg] + tbj[jj]), vh, vl);
          ch[m * 136 + j] = vh;
          cl[m * 136 + j] = vl;
        }
  }
  __syncthreads();

  // GEMM2: gi = cs @ wih1^T (nt g*8+jt), gh = h @ whh1^T (nt 24+g*8+jt)
  f32x4 acc2[2][2][6] = {};
#pragma unroll
  for (int ks = 0; ks < 4; ks++) {
    bf16x8 c0h = *(const bf16x8*)&ch[mrow * 136 + ks * 32 + kq];
    bf16x8 c0l = *(const bf16x8*)&cl[mrow * 136 + ks * 32 + kq];
    bf16x8 c1h = *(const bf16x8*)&ch[(16 + mrow) * 136 + ks * 32 + kq];
    bf16x8 c1l = *(const bf16x8*)&cl[(16 + mrow) * 136 + ks * 32 + kq];
    bf16x8 x0h = *(const bf16x8*)&hh[mrow * 136 + ks * 32 + kq];
    bf16x8 x0l = *(const bf16x8*)&hl[mrow * 136 + ks * 32 + kq];
    bf16x8 x1h = *(const bf16x8*)&hh[(16 + mrow) * 136 + ks * 32 + kq];
    bf16x8 x1l = *(const bf16x8*)&hl[(16 + mrow) * 136 + ks * 32 + kq];
#pragma unroll
    for (int jj = 0; jj < 2; jj++) {
      int jt = wv + jj * 4;
#pragma unroll
      for (int g = 0; g < 3; g++) {
        int nt = g * 8 + jt;
        size_t base = (size_t)((nt * 4 + ks) * 64 + lane) * 8;
        bf16x8 bh = *(const bf16x8*)&w2ph[base];
        bf16x8 bl = *(const bf16x8*)&w2pl[base];
        MFMA3(acc2[0][jj][g], c0h, c0l, bh, bl);
        MFMA3(acc2[1][jj][g], c1h, c1l, bh, bl);
      }
#pragma unroll
      for (int g = 0; g < 3; g++) {
        int nt = 24 + g * 8 + jt;
        size_t base = (size_t)((nt * 4 + ks) * 64 + lane) * 8;
        bf16x8 bh = *(const bf16x8*)&w2ph[base];
        bf16x8 bl = *(const bf16x8*)&w2pl[base];
        MFMA3(acc2[0][jj][3 + g], x0h, x0l, bh, bl);
        MFMA3(acc2[1][jj][3 + g], x1h, x1l, bh, bl);
      }
    }
  }

  // GRU epilogue + deg scale
  float bir[2], biz[2], bin_[2], bhr[2], bhz[2], bhn[2];
#pragma unroll
  for (int jj = 0; jj < 2; jj++) {
    int j = (wv + jj * 4) * 16 + mrow;
    bir[jj] = bih1[j]; biz[jj] = bih1[j + 128]; bin_[jj] = bih1[j + 256];
    bhr[jj] = bhh1[j]; bhz[jj] = bhh1[j + 128]; bhn[jj] = bhh1[j + 256];
  }
#pragma unroll
  for (int mt = 0; mt < 2; mt++) {
#pragma unroll
    for (int reg = 0; reg < 4; reg++) {
      int m = mt * 16 + quad * 4 + reg;
      float dd = deg_lds[m];
#pragma unroll
      for (int jj = 0; jj < 2; jj++) {
        int j = (wv + jj * 4) * 16 + mrow;
        float gir = acc2[mt][jj][0][reg] + bir[jj];
        float giz = acc2[mt][jj][1][reg] + biz[jj];
        float gin = acc2[mt][jj][2][reg] + bin_[jj];
        float ghr = acc2[mt][jj][3][reg] + bhr[jj];
        float ghz = acc2[mt][jj][4][reg] + bhz[jj];
        float ghn = acc2[mt][jj][5][reg] + bhn[jj];
        float r = sigm(gir + ghr);
        float z = sigm(giz + ghz);
        float nn = tanhf(fmaf(r, ghn, gin));
        float hfull = (float)(*(const __bf16*)&hh[m * 136 + j]) +
                      (float)(*(const __bf16*)&hl[m * 136 + j]);
        out[(size_t)(n0 + m) * 128 + j] = dd * ((1.f - z) * nn + z * hfull);
      }
    }
  }
}

extern "C" void kernel_launch(void* const* d_in, const int* in_sizes, int n_in,
                              void* d_out, int out_size, void* d_ws, size_t ws_size,
                              hipStream_t stream) {
  const float* x     = (const float*)d_in[0];
  const int*   edge  = (const int*)d_in[1];
  const float* attw0 = (const float*)d_in[4];
  const float* attb0 = (const float*)d_in[5];
  const float* wih0  = (const float*)d_in[6];
  const float* whh0  = (const float*)d_in[7];
  const float* bih0  = (const float*)d_in[8];
  const float* bhh0  = (const float*)d_in[9];
  const float* attw1 = (const float*)d_in[12];
  const float* attb1 = (const float*)d_in[13];
  const float* wih1  = (const float*)d_in[14];
  const float* whh1  = (const float*)d_in[15];
  const float* bih1  = (const float*)d_in[16];
  const float* bhh1  = (const float*)d_in[17];

  float* ws   = (float*)d_ws;
  float* x1   = ws;
  int*   deg  = (int*)(ws + 25600000);
  float* rwt0 = ws + 25800000;
  float* rwh0 = ws + 25800128;
  unsigned short* wp = (unsigned short*)(ws + 25800512);
  unsigned short* w0ph = wp;             // 49152 shorts
  unsigned short* w0pl = wp + 49152;
  unsigned short* w1ph = wp + 98304;     // 16384
  unsigned short* w1pl = wp + 114688;
  unsigned short* w2ph = wp + 131072;    // 98304
  unsigned short* w2pl = wp + 229376;    // end 327680 shorts

  const int* dst = edge + NE;  // edge_index[1]

  hipMemsetAsync(deg, 0, NN * sizeof(int), stream);
  hist_kernel<<<(NE + 255) / 256, 256, 0, stream>>>(dst, deg);
  prep_kernel<<<1, 512, 0, stream>>>(attw0, whh0, rwt0, rwh0);
  pack_kernel<<<80, 256, 0, stream>>>(wih0, attw1, wih1, whh1,
                                      w0ph, w0pl, w1ph, w1pl, w2ph, w2pl);
  layer0_kernel<<<NN / 32, 256, 0, stream>>>(x, attb0, w0ph, w0pl, bih0, bhh0,
                                             rwt0, rwh0, deg, x1);
  layer1_kernel<<<NN / 32, 256, 0, stream>>>(x1, attb1, w1ph, w1pl, w2ph, w2pl,
                                             bih1, bhh1, deg, (float*)d_out);
}

// Round 5
// 501.270 us; speedup vs baseline: 5.6022x; 1.1516x over previous
//
#include <hip/hip_runtime.h>
#include <cmath>

#define NN 200000
#define NE 600000

typedef __bf16 bf16x8 __attribute__((ext_vector_type(8)));
typedef float f32x4 __attribute__((ext_vector_type(4)));

#define LOG2E 1.44269504088896340736f
__device__ __forceinline__ float fexp2(float x) { return __builtin_amdgcn_exp2f(x); }
__device__ __forceinline__ float frcp(float x) { return __builtin_amdgcn_rcpf(x); }
// sigmoid: 1/(1+e^-v)  (v_exp + v_rcp, ~4 inst vs libm ~30)
__device__ __forceinline__ float sigm(float v) { return frcp(1.0f + fexp2(-LOG2E * v)); }
// tanh via e^{-2|v|} (HW exp handles full range; large |v| -> t=0 -> r=1)
__device__ __forceinline__ float ftanh(float v) {
  float t = fexp2(-2.0f * LOG2E * fabsf(v));
  float r = (1.0f - t) * frcp(1.0f + t);
  return __builtin_copysignf(r, v);
}
// elu: v>0 ? v : e^v - 1  (abs err ~2^-24 near 0 — fine for absmax budget)
__device__ __forceinline__ float eluf(float v) { return v > 0.0f ? v : fexp2(LOG2E * v) - 1.0f; }

__device__ __forceinline__ unsigned short bfr(float f) {  // f32 -> bf16 RNE
  unsigned u = __float_as_uint(f);
  u += 0x7FFFu + ((u >> 16) & 1u);
  return (unsigned short)(u >> 16);
}
// split fp32 into hi+lo bf16 (exact to ~2^-18 relative)
__device__ __forceinline__ void bsplit(float v, unsigned short& hi, unsigned short& lo) {
  unsigned short h = bfr(v);
  float hf = __uint_as_float(((unsigned)h) << 16);
  hi = h;
  lo = bfr(v - hf);
}

// ---------------- ws layout (float offsets) ----------------
// x1 [25,600,000] @0 ; deg(int)[200,000] @25,600,000 ; rwt0[128] @25,800,000 ;
// rwh0[384] @25,800,128 ; packed bf16 weight frags (shorts) @float 25,800,512:
//   w0ph 49152 | w0pl 49152 | w1ph 16384 | w1pl 16384 | w2ph 98304 | w2pl 98304

__global__ __launch_bounds__(256) void hist_kernel(const int* __restrict__ dst,
                                                   int* __restrict__ deg) {
  int e = blockIdx.x * 256 + threadIdx.x;
  if (e < NE) atomicAdd(&deg[dst[e]], 1);
}

__global__ __launch_bounds__(512) void prep_kernel(const float* __restrict__ attw0,
                                                   const float* __restrict__ whh0,
                                                   float* __restrict__ rwt0,
                                                   float* __restrict__ rwh0) {
  int t = threadIdx.x;
  if (t < 128) {
    float s = 0.f;
    for (int k = 0; k < 128; k++) s += attw0[t * 128 + k];
    rwt0[t] = s;
  } else {
    int j = t - 128;
    float s = 0.f;
    for (int k = 0; k < 128; k++) s += whh0[j * 128 + k];
    rwh0[j] = s;
  }
}

// Pack weights into MFMA B-fragment order, split hi/lo bf16:
// frag[((nt*4+ks)*64+lane)*8 + j] = W[nt*16+(lane&15)][ks*32+(lane>>4)*8+j]
__global__ __launch_bounds__(256) void pack_kernel(
    const float* __restrict__ wih0, const float* __restrict__ tw1,
    const float* __restrict__ wih1, const float* __restrict__ whh1,
    unsigned short* __restrict__ w0ph, unsigned short* __restrict__ w0pl,
    unsigned short* __restrict__ w1ph, unsigned short* __restrict__ w1pl,
    unsigned short* __restrict__ w2ph, unsigned short* __restrict__ w2pl) {
  int g = blockIdx.x * 256 + threadIdx.x;  // one 8-element lane-frag
  unsigned short *PH, *PL;
  const float* row;
  int l;
  if (g < 6144) { l = g; PH = w0ph; PL = w0pl; }
  else if (g < 8192) { l = g - 6144; PH = w1ph; PL = w1pl; }
  else if (g < 20480) { l = g - 8192; PH = w2ph; PL = w2pl; }
  else return;
  int lane = l & 63, ks = (l >> 6) & 3, nt = l >> 8;
  int n = nt * 16 + (lane & 15);
  int k0 = ks * 32 + (lane >> 4) * 8;
  if (g < 6144) row = wih0 + n * 128;
  else if (g < 8192) row = tw1 + n * 128;
  else row = (n < 384) ? wih1 + n * 128 : whh1 + (n - 384) * 128;
  unsigned uh[4], ul[4];
  for (int p = 0; p < 4; p++) {
    unsigned short ah, al, bh, bl;
    bsplit(row[k0 + 2 * p], ah, al);
    bsplit(row[k0 + 2 * p + 1], bh, bl);
    uh[p] = (unsigned)ah | ((unsigned)bh << 16);
    ul[p] = (unsigned)al | ((unsigned)bl << 16);
  }
  *(uint4*)&PH[l * 8] = make_uint4(uh[0], uh[1], uh[2], uh[3]);
  *(uint4*)&PL[l * 8] = make_uint4(ul[0], ul[1], ul[2], ul[3]);
}

#define MFMA3(accv, ah, al, bh, bl)                                          \
  accv = __builtin_amdgcn_mfma_f32_16x16x32_bf16(ah, bh, accv, 0, 0, 0);     \
  accv = __builtin_amdgcn_mfma_f32_16x16x32_bf16(ah, bl, accv, 0, 0, 0);     \
  accv = __builtin_amdgcn_mfma_f32_16x16x32_bf16(al, bh, accv, 0, 0, 0);

// ---------------- layer 0: M=32 nodes/block, 256 threads (4 waves) ----------------
__global__ __launch_bounds__(256, 2) void layer0_kernel(
    const float* __restrict__ x, const float* __restrict__ tb0,
    const unsigned short* __restrict__ w0ph, const unsigned short* __restrict__ w0pl,
    const float* __restrict__ bih0, const float* __restrict__ bhh0,
    const float* __restrict__ rwt0, const float* __restrict__ rwh0,
    const int* __restrict__ deg, float* __restrict__ x1) {
  __shared__ float s_lds[32];
  __shared__ float deg_lds[32];
  __shared__ unsigned short csh[32 * 136];
  __shared__ unsigned short csl[32 * 136];

  const int tid = threadIdx.x;
  const int lane = tid & 63;
  const int wv = tid >> 6;
  const int n0 = blockIdx.x * 32;

  if (tid < 32) deg_lds[tid] = (float)deg[n0 + tid];

  // s_m = rowsum(x[m])
  {
    int m = tid >> 3, c = (tid & 7) * 16;
    const float4* xr = (const float4*)(x + (size_t)(n0 + m) * 128 + c);
    float a = 0.f;
#pragma unroll
    for (int q = 0; q < 4; q++) { float4 v = xr[q]; a += v.x + v.y + v.z + v.w; }
#pragma unroll
    for (int o = 1; o < 8; o <<= 1) a += __shfl_xor(a, o, 64);
    if ((tid & 7) == 0) s_lds[m] = a;
  }
  __syncthreads();

  // cs0[m][k] = elu(s_m * rwt0[k] + tb0[k]) -> split bf16 LDS
  {
    int m = tid >> 3, c0 = (tid & 7) * 16;
    float s = s_lds[m];
#pragma unroll
    for (int q = 0; q < 4; q++) {
      int k = c0 + q * 4;
      unsigned short h0, l0, h1, l1, h2, l2, h3, l3;
      bsplit(eluf(fmaf(s, rwt0[k], tb0[k])), h0, l0);
      bsplit(eluf(fmaf(s, rwt0[k + 1], tb0[k + 1])), h1, l1);
      bsplit(eluf(fmaf(s, rwt0[k + 2], tb0[k + 2])), h2, l2);
      bsplit(eluf(fmaf(s, rwt0[k + 3], tb0[k + 3])), h3, l3);
      *(uint2*)&csh[m * 136 + k] =
          make_uint2((unsigned)h0 | ((unsigned)h1 << 16), (unsigned)h2 | ((unsigned)h3 << 16));
      *(uint2*)&csl[m * 136 + k] =
          make_uint2((unsigned)l0 | ((unsigned)l1 << 16), (unsigned)l2 | ((unsigned)l3 << 16));
    }
  }
  __syncthreads();

  // gi = cs0 @ wih0^T via split-bf16 MFMA
  const int mrow = lane & 15;
  const int kq = (lane >> 4) * 8;
  const int quad = lane >> 4;
  f32x4 acc[2][2][3] = {};
#pragma unroll
  for (int ks = 0; ks < 4; ks++) {
    bf16x8 a0h = *(const bf16x8*)&csh[mrow * 136 + ks * 32 + kq];
    bf16x8 a0l = *(const bf16x8*)&csl[mrow * 136 + ks * 32 + kq];
    bf16x8 a1h = *(const bf16x8*)&csh[(16 + mrow) * 136 + ks * 32 + kq];
    bf16x8 a1l = *(const bf16x8*)&csl[(16 + mrow) * 136 + ks * 32 + kq];
#pragma unroll
    for (int jj = 0; jj < 2; jj++) {
      int jt = wv + jj * 4;
#pragma unroll
      for (int g = 0; g < 3; g++) {
        int nt = g * 8 + jt;
        size_t base = (size_t)((nt * 4 + ks) * 64 + lane) * 8;
        bf16x8 bh = *(const bf16x8*)&w0ph[base];
        bf16x8 bl = *(const bf16x8*)&w0pl[base];
        MFMA3(acc[0][jj][g], a0h, a0l, bh, bl);
        MFMA3(acc[1][jj][g], a1h, a1l, bh, bl);
      }
    }
  }

  // GRU epilogue (h = s broadcast, gh = s*rwh0 + bhh0), scale by deg
  float bir[2], biz[2], bin_[2], bhr[2], bhz[2], bhn[2], rwr[2], rwz[2], rwn[2];
#pragma unroll
  for (int jj = 0; jj < 2; jj++) {
    int j = (wv + jj * 4) * 16 + mrow;
    bir[jj] = bih0[j]; biz[jj] = bih0[j + 128]; bin_[jj] = bih0[j + 256];
    bhr[jj] = bhh0[j]; bhz[jj] = bhh0[j + 128]; bhn[jj] = bhh0[j + 256];
    rwr[jj] = rwh0[j]; rwz[jj] = rwh0[j + 128]; rwn[jj] = rwh0[j + 256];
  }
#pragma unroll
  for (int mt = 0; mt < 2; mt++) {
#pragma unroll
    for (int reg = 0; reg < 4; reg++) {
      int m = mt * 16 + quad * 4 + reg;
      float s = s_lds[m];
      float dd = deg_lds[m];
#pragma unroll
      for (int jj = 0; jj < 2; jj++) {
        float gir = acc[mt][jj][0][reg] + bir[jj];
        float giz = acc[mt][jj][1][reg] + biz[jj];
        float gin = acc[mt][jj][2][reg] + bin_[jj];
        float ghr = fmaf(s, rwr[jj], bhr[jj]);
        float ghz = fmaf(s, rwz[jj], bhz[jj]);
        float ghn = fmaf(s, rwn[jj], bhn[jj]);
        float r = sigm(gir + ghr);
        float z = sigm(giz + ghz);
        float nn = ftanh(fmaf(r, ghn, gin));
        int j = (wv + jj * 4) * 16 + mrow;
        x1[(size_t)(n0 + m) * 128 + j] = dd * ((1.f - z) * nn + z * s);
      }
    }
  }
}

// ---------------- layer 1: M=32 nodes/block, 256 threads (4 waves) ----------------
__global__ __launch_bounds__(256, 2) void layer1_kernel(
    const float* __restrict__ x1, const float* __restrict__ tb1,
    const unsigned short* __restrict__ w1ph, const unsigned short* __restrict__ w1pl,
    const unsigned short* __restrict__ w2ph, const unsigned short* __restrict__ w2pl,
    const float* __restrict__ bih1, const float* __restrict__ bhh1,
    const int* __restrict__ deg, float* __restrict__ out) {
  __shared__ unsigned short hh[32 * 136];
  __shared__ unsigned short hl[32 * 136];
  __shared__ unsigned short ch[32 * 136];
  __shared__ unsigned short cl[32 * 136];
  __shared__ float deg_lds[32];

  const int tid = threadIdx.x;
  const int lane = tid & 63;
  const int wv = tid >> 6;
  const int n0 = blockIdx.x * 32;
  const int mrow = lane & 15;
  const int kq = (lane >> 4) * 8;
  const int quad = lane >> 4;

  if (tid < 32) deg_lds[tid] = (float)deg[n0 + tid];

  // stage h = x1 tile, split bf16
  {
    int m = tid >> 3, c0 = (tid & 7) * 16;
    const float4* xr = (const float4*)(x1 + (size_t)(n0 + m) * 128 + c0);
#pragma unroll
    for (int q = 0; q < 4; q++) {
      float4 v = xr[q];
      unsigned short h0, l0, h1, l1, h2, l2, h3, l3;
      bsplit(v.x, h0, l0); bsplit(v.y, h1, l1);
      bsplit(v.z, h2, l2); bsplit(v.w, h3, l3);
      *(uint2*)&hh[m * 136 + c0 + q * 4] =
          make_uint2((unsigned)h0 | ((unsigned)h1 << 16), (unsigned)h2 | ((unsigned)h3 << 16));
      *(uint2*)&hl[m * 136 + c0 + q * 4] =
          make_uint2((unsigned)l0 | ((unsigned)l1 << 16), (unsigned)l2 | ((unsigned)l3 << 16));
    }
  }
  __syncthreads();

  // GEMM1: t1 = h @ tw1^T ; cs = elu(t1 + tb1) -> split bf16 LDS
  f32x4 acc1[2][2] = {};
#pragma unroll
  for (int ks = 0; ks < 4; ks++) {
    bf16x8 a0h = *(const bf16x8*)&hh[mrow * 136 + ks * 32 + kq];
    bf16x8 a0l = *(const bf16x8*)&hl[mrow * 136 + ks * 32 + kq];
    bf16x8 a1h = *(const bf16x8*)&hh[(16 + mrow) * 136 + ks * 32 + kq];
    bf16x8 a1l = *(const bf16x8*)&hl[(16 + mrow) * 136 + ks * 32 + kq];
#pragma unroll
    for (int jj = 0; jj < 2; jj++) {
      int nt = wv + jj * 4;
      size_t base = (size_t)((nt * 4 + ks) * 64 + lane) * 8;
      bf16x8 bh = *(const bf16x8*)&w1ph[base];
      bf16x8 bl = *(const bf16x8*)&w1pl[base];
      MFMA3(acc1[0][jj], a0h, a0l, bh, bl);
      MFMA3(acc1[1][jj], a1h, a1l, bh, bl);
    }
  }
  {
    float tbj[2];
#pragma unroll
    for (int jj = 0; jj < 2; jj++) tbj[jj] = tb1[(wv + jj * 4) * 16 + mrow];
#pragma unroll
    for (int mt = 0; mt < 2; mt++)
#pragma unroll
      for (int jj = 0; jj < 2; jj++)
#pragma unroll
        for (int reg = 0; reg < 4; reg++) {
          int m = mt * 16 + quad * 4 + reg;
          unsigned short vh, vl;
          bsplit(eluf(acc1[mt][jj][reg] + tbj[jj]), vh, vl);
          // pair adjacent lanes (mrow even/odd) -> single b32 stores, conflict-light
          unsigned pv = (unsigned)vh | ((unsigned)vl << 16);
          unsigned pu = __shfl_xor(pv, 1, 64);
          if ((lane & 1) == 0) {
            int j = (wv + jj * 4) * 16 + mrow;  // mrow even here
            unsigned hpack = (pv & 0xFFFFu) | (pu << 16);
            unsigned lpack = (pv >> 16) | (pu & 0xFFFF0000u);
            *(unsigned*)&ch[m * 136 + j] = hpack;
            *(unsigned*)&cl[m * 136 + j] = lpack;
          }
        }
  }
  __syncthreads();

  // GEMM2: gi = cs @ wih1^T (nt g*8+jt), gh = h @ whh1^T (nt 24+g*8+jt)
  f32x4 acc2[2][2][6] = {};
#pragma unroll
  for (int ks = 0; ks < 4; ks++) {
    bf16x8 c0h = *(const bf16x8*)&ch[mrow * 136 + ks * 32 + kq];
    bf16x8 c0l = *(const bf16x8*)&cl[mrow * 136 + ks * 32 + kq];
    bf16x8 c1h = *(const bf16x8*)&ch[(16 + mrow) * 136 + ks * 32 + kq];
    bf16x8 c1l = *(const bf16x8*)&cl[(16 + mrow) * 136 + ks * 32 + kq];
    bf16x8 x0h = *(const bf16x8*)&hh[mrow * 136 + ks * 32 + kq];
    bf16x8 x0l = *(const bf16x8*)&hl[mrow * 136 + ks * 32 + kq];
    bf16x8 x1h = *(const bf16x8*)&hh[(16 + mrow) * 136 + ks * 32 + kq];
    bf16x8 x1l = *(const bf16x8*)&hl[(16 + mrow) * 136 + ks * 32 + kq];
#pragma unroll
    for (int jj = 0; jj < 2; jj++) {
      int jt = wv + jj * 4;
#pragma unroll
      for (int g = 0; g < 3; g++) {
        int nt = g * 8 + jt;
        size_t base = (size_t)((nt * 4 + ks) * 64 + lane) * 8;
        bf16x8 bh = *(const bf16x8*)&w2ph[base];
        bf16x8 bl = *(const bf16x8*)&w2pl[base];
        MFMA3(acc2[0][jj][g], c0h, c0l, bh, bl);
        MFMA3(acc2[1][jj][g], c1h, c1l, bh, bl);
      }
#pragma unroll
      for (int g = 0; g < 3; g++) {
        int nt = 24 + g * 8 + jt;
        size_t base = (size_t)((nt * 4 + ks) * 64 + lane) * 8;
        bf16x8 bh = *(const bf16x8*)&w2ph[base];
        bf16x8 bl = *(const bf16x8*)&w2pl[base];
        MFMA3(acc2[0][jj][3 + g], x0h, x0l, bh, bl);
        MFMA3(acc2[1][jj][3 + g], x1h, x1l, bh, bl);
      }
    }
  }

  // GRU epilogue + deg scale
  float bir[2], biz[2], bin_[2], bhr[2], bhz[2], bhn[2];
#pragma unroll
  for (int jj = 0; jj < 2; jj++) {
    int j = (wv + jj * 4) * 16 + mrow;
    bir[jj] = bih1[j]; biz[jj] = bih1[j + 128]; bin_[jj] = bih1[j + 256];
    bhr[jj] = bhh1[j]; bhz[jj] = bhh1[j + 128]; bhn[jj] = bhh1[j + 256];
  }
#pragma unroll
  for (int mt = 0; mt < 2; mt++) {
#pragma unroll
    for (int reg = 0; reg < 4; reg++) {
      int m = mt * 16 + quad * 4 + reg;
      float dd = deg_lds[m];
#pragma unroll
      for (int jj = 0; jj < 2; jj++) {
        int j = (wv + jj * 4) * 16 + mrow;
        float gir = acc2[mt][jj][0][reg] + bir[jj];
        float giz = acc2[mt][jj][1][reg] + biz[jj];
        float gin = acc2[mt][jj][2][reg] + bin_[jj];
        float ghr = acc2[mt][jj][3][reg] + bhr[jj];
        float ghz = acc2[mt][jj][4][reg] + bhz[jj];
        float ghn = acc2[mt][jj][5][reg] + bhn[jj];
        float r = sigm(gir + ghr);
        float z = sigm(giz + ghz);
        float nn = ftanh(fmaf(r, ghn, gin));
        float hfull = (float)(*(const __bf16*)&hh[m * 136 + j]) +
                      (float)(*(const __bf16*)&hl[m * 136 + j]);
        out[(size_t)(n0 + m) * 128 + j] = dd * ((1.f - z) * nn + z * hfull);
      }
    }
  }
}

extern "C" void kernel_launch(void* const* d_in, const int* in_sizes, int n_in,
                              void* d_out, int out_size, void* d_ws, size_t ws_size,
                              hipStream_t stream) {
  const float* x     = (const float*)d_in[0];
  const int*   edge  = (const int*)d_in[1];
  const float* attw0 = (const float*)d_in[4];
  const float* attb0 = (const float*)d_in[5];
  const float* wih0  = (const float*)d_in[6];
  const float* whh0  = (const float*)d_in[7];
  const float* bih0  = (const float*)d_in[8];
  const float* bhh0  = (const float*)d_in[9];
  const float* attw1 = (const float*)d_in[12];
  const float* attb1 = (const float*)d_in[13];
  const float* wih1  = (const float*)d_in[14];
  const float* whh1  = (const float*)d_in[15];
  const float* bih1  = (const float*)d_in[16];
  const float* bhh1  = (const float*)d_in[17];

  float* ws   = (float*)d_ws;
  float* x1   = ws;
  int*   deg  = (int*)(ws + 25600000);
  float* rwt0 = ws + 25800000;
  float* rwh0 = ws + 25800128;
  unsigned short* wp = (unsigned short*)(ws + 25800512);
  unsigned short* w0ph = wp;             // 49152 shorts
  unsigned short* w0pl = wp + 49152;
  unsigned short* w1ph = wp + 98304;     // 16384
  unsigned short* w1pl = wp + 114688;
  unsigned short* w2ph = wp + 131072;    // 98304
  unsigned short* w2pl = wp + 229376;    // end 327680 shorts

  const int* dst = edge + NE;  // edge_index[1]

  hipMemsetAsync(deg, 0, NN * sizeof(int), stream);
  hist_kernel<<<(NE + 255) / 256, 256, 0, stream>>>(dst, deg);
  prep_kernel<<<1, 512, 0, stream>>>(attw0, whh0, rwt0, rwh0);
  pack_kernel<<<80, 256, 0, stream>>>(wih0, attw1, wih1, whh1,
                                      w0ph, w0pl, w1ph, w1pl, w2ph, w2pl);
  layer0_kernel<<<NN / 32, 256, 0, stream>>>(x, attb0, w0ph, w0pl, bih0, bhh0,
                                             rwt0, rwh0, deg, x1);
  layer1_kernel<<<NN / 32, 256, 0, stream>>>(x1, attb1, w1ph, w1pl, w2ph, w2pl,
                                             bih1, bhh1, deg, (float*)d_out);
}